// Round 17
// baseline (51.367 us; speedup 1.0000x reference)
//
#include <hip/hip_runtime.h>
#include <hip/hip_bf16.h>

typedef __bf16 bf16;
typedef __attribute__((ext_vector_type(4))) __bf16 bf16x4;
typedef __attribute__((ext_vector_type(8))) __bf16 bf16x8;
typedef __attribute__((ext_vector_type(4))) float f32x4;

#define D_MODEL 1024
#define DK 128
#define LSEQ 2048
#define NQT 128
#define NB 4
// 1/sqrt(128) * log2(e): softmax runs in exp2 domain end-to-end
#define SCALE2 (0.08838834764831845f * 1.4426950408889634f)

// ---------------------------------------------------------------------------
// Kernel 0: transpose + bf16-convert weights. W[1024][128] f32 -> Wt[3][128][1024]
// Vectorized: f32x4 input loads, bf16x8 output stores (16+16 -> 4+2 instrs).
// ---------------------------------------------------------------------------
__global__ __launch_bounds__(256) void wt_kernel(
    const float* __restrict__ Wq, const float* __restrict__ Wk,
    const float* __restrict__ Wv, bf16* __restrict__ Wt)
{
    __shared__ bf16 tile[64][72];
    const float* W = (blockIdx.z == 0) ? Wq : (blockIdx.z == 1) ? Wk : Wv;
    int k0 = blockIdx.x * 64;
    int n0 = blockIdx.y * 64;
    int t  = threadIdx.x;
    #pragma unroll
    for (int i = 0; i < 4; ++i) {
        int idx = t + i * 256;
        int r = idx >> 4, c4 = (idx & 15) * 4;
        f32x4 v = *reinterpret_cast<const f32x4*>(
            &W[(size_t)(k0 + r) * DK + n0 + c4]);
        tile[c4 + 0][r] = (bf16)v[0];
        tile[c4 + 1][r] = (bf16)v[1];
        tile[c4 + 2][r] = (bf16)v[2];
        tile[c4 + 3][r] = (bf16)v[3];
    }
    __syncthreads();
    bf16* out = Wt + (size_t)blockIdx.z * DK * D_MODEL;
    #pragma unroll
    for (int i = 0; i < 2; ++i) {
        int idx = t + i * 256;
        int rr = idx >> 3, cc = (idx & 7) * 8;
        *reinterpret_cast<bf16x8*>(&out[(size_t)(n0 + rr) * D_MODEL + k0 + cc]) =
            *reinterpret_cast<const bf16x8*>(&tile[rr][cc]);
    }
}

// ---------------------------------------------------------------------------
// Kernel 1: QKV projection GEMM (R5/R9-proven, byte-identical). X f32 x Wt
// bf16, M-tile 64, BK 64, 4 waves; reg-staged double-buffer, f32->bf16 on
// LDS store. [.][72] pads: word-stride ≡ 4 (mod 32) -> b128 at bank floor.
// ---------------------------------------------------------------------------
__global__ __launch_bounds__(256) void proj_kernel(
    const float* __restrict__ X, const bf16* __restrict__ Wt,
    bf16* __restrict__ Qs, bf16* __restrict__ Kb, bf16* __restrict__ Vt)
{
    __shared__ bf16 Xs[64][72];
    __shared__ bf16 Ws[128][72];
    int mt = blockIdx.x, mat = blockIdx.y;
    const bf16* W = Wt + (size_t)mat * DK * D_MODEL;
    int t = threadIdx.x;
    int wave = t >> 6, lane = t & 63;
    int lq = lane & 15, g = lane >> 4;
    int row0 = mt * 64;

    f32x4 acc[4][2];
    #pragma unroll
    for (int m = 0; m < 4; ++m)
        #pragma unroll
        for (int n = 0; n < 2; ++n) acc[m][n] = f32x4{0.f, 0.f, 0.f, 0.f};

    f32x4  rxf[4];
    bf16x8 rw[4];
    auto LOADR = [&](int k0) {
        #pragma unroll
        for (int i = 0; i < 4; ++i) {
            int u = t + i * 256, r = u >> 4, c4 = u & 15;
            rxf[i] = *reinterpret_cast<const f32x4*>(
                &X[(size_t)(row0 + r) * D_MODEL + k0 + c4 * 4]);
        }
        #pragma unroll
        for (int i = 0; i < 4; ++i) {
            int u = t + i * 256, r = u >> 3, c8 = u & 7;
            rw[i] = *reinterpret_cast<const bf16x8*>(
                &W[(size_t)r * D_MODEL + k0 + c8 * 8]);
        }
    };
    auto STORER = [&]() {
        #pragma unroll
        for (int i = 0; i < 4; ++i) {
            int u = t + i * 256, r = u >> 4, c4 = u & 15;
            bf16x4 h;
            h[0]=(bf16)rxf[i][0]; h[1]=(bf16)rxf[i][1];
            h[2]=(bf16)rxf[i][2]; h[3]=(bf16)rxf[i][3];
            *reinterpret_cast<bf16x4*>(&Xs[r][c4 * 4]) = h;
        }
        #pragma unroll
        for (int i = 0; i < 4; ++i) {
            int u = t + i * 256, r = u >> 3, c8 = u & 7;
            *reinterpret_cast<bf16x8*>(&Ws[r][c8 * 8]) = rw[i];
        }
    };

    LOADR(0);
    for (int ks = 0; ks < 16; ++ks) {
        __syncthreads();
        STORER();
        if (ks + 1 < 16) LOADR((ks + 1) * 64);
        __syncthreads();
        #pragma unroll
        for (int kk = 0; kk < 2; ++kk) {
            bf16x8 a[4];
            #pragma unroll
            for (int mr = 0; mr < 4; ++mr)
                a[mr] = *reinterpret_cast<const bf16x8*>(&Xs[mr * 16 + lq][kk * 32 + g * 8]);
            #pragma unroll
            for (int n = 0; n < 2; ++n) {
                bf16x8 bfr = *reinterpret_cast<const bf16x8*>(
                    &Ws[wave * 32 + n * 16 + lq][kk * 32 + g * 8]);
                #pragma unroll
                for (int mr = 0; mr < 4; ++mr)
                    acc[mr][n] = __builtin_amdgcn_mfma_f32_16x16x32_bf16(a[mr], bfr, acc[mr][n], 0, 0, 0);
            }
        }
    }
    #pragma unroll
    for (int mr = 0; mr < 4; ++mr) {
        int orow = row0 + mr * 16 + g * 4;
        #pragma unroll
        for (int n = 0; n < 2; ++n) {
            int col = wave * 32 + n * 16 + lq;
            if (mat == 0) {
                #pragma unroll
                for (int r = 0; r < 4; ++r)
                    Qs[(size_t)(orow + r) * DK + col] = (bf16)(acc[mr][n][r] * SCALE2);
            } else if (mat == 1) {
                #pragma unroll
                for (int r = 0; r < 4; ++r)
                    Kb[(size_t)(orow + r) * DK + col] = (bf16)acc[mr][n][r];
            } else {
                int bb  = orow >> 11;
                int kv0 = orow & 2047;
                bf16x4 h;
                h[0]=(bf16)acc[mr][n][0]; h[1]=(bf16)acc[mr][n][1];
                h[2]=(bf16)acc[mr][n][2]; h[3]=(bf16)acc[mr][n][3];
                *reinterpret_cast<bf16x4*>(
                    &Vt[((size_t)bb * DK + col) * LSEQ + kv0]) = h;
            }
        }
    }
}

// ---------------------------------------------------------------------------
// Kernel 2: causal flash attention (R16 structure). Changes this round:
// (a) s_setprio REMOVED (A/B: 4-wave lockstep blocks = m190 regime where
//     setprio hurt; it was never isolated here);
// (b) mask applied in place on sc[] (sv[] eliminated, -16 VGPR).
// Variable KV-split, XCD-pinned batch, reg-prefetch, R14 epilogue.
// ---------------------------------------------------------------------------
__global__ __launch_bounds__(256, 3) void attn_kernel(
    const bf16* __restrict__ Qs, const bf16* __restrict__ Kb,
    const bf16* __restrict__ Vt, bf16* __restrict__ Zp,
    float* __restrict__ Mp, float* __restrict__ Lp,
    float* __restrict__ Out, int split)
{
    __shared__ bf16 Ks[64][136];
    __shared__ bf16 Vs[128][72];
    __shared__ bf16 P[4][16][72];
    int bid = blockIdx.x;
    int b, qblk, s;
    if (split) {
        int xcd = bid & 7, u = bid >> 3;      // u in [0,72)
        b = xcd >> 1;                         // XCD-pinned batch (KV L2-fit)
        int n2 = (u << 1) | (xcd & 1);        // interleave: balance XCD halves
        int q = 0, off = 0;
        while (off + ((q >> 2) + 1) <= n2) { off += (q >> 2) + 1; ++q; }
        qblk = q;
        s = n2 - off;
    } else {
        b = bid >> 5;
        qblk = bid & 31;
        s = 0;
    }
    int t = threadIdx.x;
    int wave = t >> 6, lane = t & 63;
    int lq = lane & 15, g = lane >> 4;
    int qw16 = qblk * 4 + wave;
    int qg = qw16 * 16 + lq;

    int nt = qblk + 1;                   // 64-kv tiles, same for all 4 waves
    int t0 = split ? 4 * s : 0;
    int t1 = split ? min(4 * s + 4, nt) : nt;

    const bf16* Kbase = Kb + (size_t)b * LSEQ * DK;
    const bf16* Vbase = Vt + (size_t)b * DK * LSEQ;

    const bf16* Qrow = Qs + ((size_t)b * LSEQ + qg) * DK;
    bf16x8 qf[4];
    #pragma unroll
    for (int ks = 0; ks < 4; ++ks)
        qf[ks] = *reinterpret_cast<const bf16x8*>(&Qrow[ks * 32 + g * 8]);

    f32x4 z[8];
    #pragma unroll
    for (int i = 0; i < 8; ++i) z[i] = f32x4{0.f, 0.f, 0.f, 0.f};
    float mrun = -3.0e38f, lrun = 0.f;

    bf16x8 kreg[4], vreg[4];
    auto LOADKV = [&](int kvb) {
        #pragma unroll
        for (int i = 0; i < 4; ++i) {        // K: 64 rows x 16 chunks
            int u = t + i * 256, r = u >> 4, c = u & 15;
            kreg[i] = *reinterpret_cast<const bf16x8*>(
                &Kbase[(size_t)(kvb + r) * DK + c * 8]);
        }
        #pragma unroll
        for (int i = 0; i < 4; ++i) {        // V: 128 rows x 8 chunks
            int u = t + i * 256, d = u >> 3, c = u & 7;
            vreg[i] = *reinterpret_cast<const bf16x8*>(
                &Vbase[(size_t)d * LSEQ + kvb + c * 8]);
        }
    };
    auto STOREKV = [&]() {
        #pragma unroll
        for (int i = 0; i < 4; ++i) {
            int u = t + i * 256, r = u >> 4, c = u & 15;
            *reinterpret_cast<bf16x8*>(&Ks[r][c * 8]) = kreg[i];
        }
        #pragma unroll
        for (int i = 0; i < 4; ++i) {
            int u = t + i * 256, d = u >> 3, c = u & 7;
            *reinterpret_cast<bf16x8*>(&Vs[d][c * 8]) = vreg[i];
        }
    };

    LOADKV(t0 * 64);
    for (int ti = t0; ti < t1; ++ti) {
        int kvb = ti * 64;
        __syncthreads();             // prev tile's readers done
        STOREKV();
        if (ti + 1 < t1) LOADKV((ti + 1) * 64);   // hide under compute
        __syncthreads();             // LDS tile visible

        f32x4 sc[4];
        #pragma unroll
        for (int jj = 0; jj < 4; ++jj) sc[jj] = f32x4{0.f, 0.f, 0.f, 0.f};
        #pragma unroll
        for (int jj = 0; jj < 4; ++jj)
            #pragma unroll
            for (int ks = 0; ks < 4; ++ks) {
                bf16x8 a = *reinterpret_cast<const bf16x8*>(
                    &Ks[jj * 16 + lq][ks * 32 + g * 8]);
                sc[jj] = __builtin_amdgcn_mfma_f32_16x16x32_bf16(a, qf[ks], sc[jj], 0, 0, 0);
            }

        // mask in place (diagonal tile only)
        if (ti == nt - 1) {
            #pragma unroll
            for (int jj = 0; jj < 4; ++jj)
                #pragma unroll
                for (int r = 0; r < 4; ++r) {
                    int kv0 = kvb + jj * 16 + g * 4 + r;
                    if (kv0 > qg) sc[jj][r] = -3.0e38f;
                }
        }
        float mt = sc[0][0];
        #pragma unroll
        for (int jj = 0; jj < 4; ++jj)
            #pragma unroll
            for (int r = 0; r < 4; ++r) mt = fmaxf(mt, sc[jj][r]);
        mt = fmaxf(mt, __shfl_xor(mt, 16));
        mt = fmaxf(mt, __shfl_xor(mt, 32));
        if (!__all(mt <= mrun)) {
            float mnew  = fmaxf(mrun, mt);
            float alpha = exp2f(mrun - mnew);
            lrun *= alpha;
            #pragma unroll
            for (int i = 0; i < 8; ++i) {
                z[i][0] *= alpha; z[i][1] *= alpha; z[i][2] *= alpha; z[i][3] *= alpha;
            }
            mrun = mnew;
        }
        float psum = 0.f;
        #pragma unroll
        for (int jj = 0; jj < 4; ++jj) {
            bf16x4 pb;
            #pragma unroll
            for (int r = 0; r < 4; ++r) {
                float e = exp2f(sc[jj][r] - mrun);
                psum += e;
                pb[r] = (bf16)e;
            }
            *reinterpret_cast<bf16x4*>(&P[wave][lq][jj * 16 + g * 4]) = pb;
        }
        psum += __shfl_xor(psum, 16);
        psum += __shfl_xor(psum, 32);
        lrun += psum;
        #pragma unroll
        for (int sl = 0; sl < 2; ++sl) {
            bf16x8 pf = *reinterpret_cast<const bf16x8*>(&P[wave][lq][sl * 32 + g * 8]);
            #pragma unroll
            for (int dt = 0; dt < 8; ++dt) {
                bf16x8 av = *reinterpret_cast<const bf16x8*>(
                    &Vs[dt * 16 + lq][sl * 32 + g * 8]);
                z[dt] = __builtin_amdgcn_mfma_f32_16x16x32_bf16(av, pf, z[dt], 0, 0, 0);
            }
        }
    }

    int S = (qblk >> 2) + 1;
    if (!split || S == 1) {
        // this block owns the whole kv range for its rows: write Out directly
        float inv = 1.f / lrun;
        float* orow = Out + ((size_t)b * LSEQ + qg) * DK;
        #pragma unroll
        for (int dt = 0; dt < 8; ++dt) {
            f32x4 v;
            v[0]=z[dt][0]*inv; v[1]=z[dt][1]*inv; v[2]=z[dt][2]*inv; v[3]=z[dt][3]*inv;
            *reinterpret_cast<f32x4*>(&orow[dt * 16 + g * 4]) = v;
        }
    } else {
        size_t T = ((size_t)(b * NQT + qw16) * 8 + s);   // stride 8 slices
        bf16* zp = Zp + T * (16 * 128);
        #pragma unroll
        for (int dt = 0; dt < 8; ++dt) {
            bf16x4 h;
            h[0]=(bf16)z[dt][0]; h[1]=(bf16)z[dt][1];
            h[2]=(bf16)z[dt][2]; h[3]=(bf16)z[dt][3];
            *reinterpret_cast<bf16x4*>(&zp[lq * 128 + dt * 16 + g * 4]) = h;
        }
        if (g == 0) {
            Mp[T * 16 + lq] = mrun;
            Lp[T * 16 + lq] = lrun;
        }
    }
}

// ---------------------------------------------------------------------------
// Kernel 3: merge split-KV partials (bf16 Zp). qblk 0-3 (qt<16) were stored
// directly by attn -> grid covers qt 16..127 only. S(qt) = (qt>>4)+1 >= 2.
// ---------------------------------------------------------------------------
__global__ __launch_bounds__(256) void combine_kernel(
    const bf16* __restrict__ Zp, const float* __restrict__ Mp,
    const float* __restrict__ Lp, float* __restrict__ Out)
{
    int qt = blockIdx.x + 16, b = blockIdx.y;
    int S  = (qt >> 4) + 1;
    int t  = threadIdx.x;
    int r  = t >> 4;
    int d0 = (t & 15) * 8;
    size_t Tbase = (size_t)(b * NQT + qt) * 8;

    float m = -3.0e38f;
    for (int s = 0; s < S; ++s)
        m = fmaxf(m, Mp[(Tbase + s) * 16 + r]);

    float L = 0.f;
    float a[8] = {0.f, 0.f, 0.f, 0.f, 0.f, 0.f, 0.f, 0.f};
    for (int s = 0; s < S; ++s) {
        float w = exp2f(Mp[(Tbase + s) * 16 + r] - m);
        L += w * Lp[(Tbase + s) * 16 + r];
        bf16x8 v = *reinterpret_cast<const bf16x8*>(
            &Zp[(Tbase + s) * (16 * 128) + r * 128 + d0]);
        #pragma unroll
        for (int j = 0; j < 8; ++j) a[j] += w * (float)v[j];
    }
    float inv = 1.f / L;
    float* orow = Out + ((size_t)b * LSEQ + qt * 16 + r) * DK + d0;
    f32x4 o0, o1;
    o0[0]=a[0]*inv; o0[1]=a[1]*inv; o0[2]=a[2]*inv; o0[3]=a[3]*inv;
    o1[0]=a[4]*inv; o1[1]=a[5]*inv; o1[2]=a[6]*inv; o1[3]=a[7]*inv;
    *reinterpret_cast<f32x4*>(&orow[0]) = o0;
    *reinterpret_cast<f32x4*>(&orow[4]) = o1;
}

// ---------------------------------------------------------------------------
extern "C" void kernel_launch(void* const* d_in, const int* in_sizes, int n_in,
                              void* d_out, int out_size, void* d_ws, size_t ws_size,
                              hipStream_t stream)
{
    const float* X  = (const float*)d_in[0];
    const float* Wq = (const float*)d_in[1];
    const float* Wk = (const float*)d_in[2];
    const float* Wv = (const float*)d_in[3];
    float* Out = (float*)d_out;

    char* ws = (char*)d_ws;
    // layout: Wt @0 (768KB) ; Qs @1MB ; Kb @3MB ; Vt @5MB ; Zp @7MB (16MB bf16) ;
    //         Mp / Lp after (256KB each). Total ~23.5MB.
    bf16* Wt = (bf16*)(ws);
    bf16* Qs = (bf16*)(ws + ((size_t)1 << 20));
    bf16* Kb = (bf16*)(ws + ((size_t)3 << 20));
    bf16* Vt = (bf16*)(ws + ((size_t)5 << 20));
    size_t base = (size_t)7 << 20;

    size_t zp_bytes = (size_t)NB * NQT * 8 * 16 * 128 * 2;   // 16 MB (bf16)
    size_t ml_bytes = (size_t)NB * NQT * 8 * 16 * 4;         // 256 KB each
    int split = (ws_size >= base + zp_bytes + 2 * ml_bytes) ? 1 : 0;

    bf16*  Zp = (bf16*)(ws + base);
    float* Mp = (float*)(ws + base + zp_bytes);
    float* Lp = (float*)(ws + base + zp_bytes + ml_bytes);

    hipLaunchKernelGGL(wt_kernel,   dim3(16, 2, 3), dim3(256), 0, stream, Wq, Wk, Wv, Wt);
    hipLaunchKernelGGL(proj_kernel, dim3(128, 3),   dim3(256), 0, stream, X, Wt, Qs, Kb, Vt);
    hipLaunchKernelGGL(attn_kernel, dim3(split ? 576 : NB * 32), dim3(256), 0, stream,
                       Qs, Kb, Vt, Zp, Mp, Lp, Out, split);
    if (split)
        hipLaunchKernelGGL(combine_kernel, dim3(112, NB), dim3(256), 0, stream,
                           Zp, Mp, Lp, Out);
}

// Round 18
// 50.693 us; speedup vs baseline: 1.0133x; 1.0133x over previous
//
#include <hip/hip_runtime.h>
#include <hip/hip_bf16.h>

typedef __bf16 bf16;
typedef __attribute__((ext_vector_type(4))) __bf16 bf16x4;
typedef __attribute__((ext_vector_type(8))) __bf16 bf16x8;
typedef __attribute__((ext_vector_type(4))) float f32x4;

#define D_MODEL 1024
#define DK 128
#define LSEQ 2048
#define NQT 128
#define NB 4
// 1/sqrt(128) * log2(e): softmax runs in exp2 domain end-to-end
#define SCALE2 (0.08838834764831845f * 1.4426950408889634f)

// ---------------------------------------------------------------------------
// Kernel 0: transpose + bf16-convert weights. W[1024][128] f32 -> Wt[3][128][1024]
// Vectorized (R17-proven): f32x4 loads, bf16x8 stores.
// ---------------------------------------------------------------------------
__global__ __launch_bounds__(256) void wt_kernel(
    const float* __restrict__ Wq, const float* __restrict__ Wk,
    const float* __restrict__ Wv, bf16* __restrict__ Wt)
{
    __shared__ bf16 tile[64][72];
    const float* W = (blockIdx.z == 0) ? Wq : (blockIdx.z == 1) ? Wk : Wv;
    int k0 = blockIdx.x * 64;
    int n0 = blockIdx.y * 64;
    int t  = threadIdx.x;
    #pragma unroll
    for (int i = 0; i < 4; ++i) {
        int idx = t + i * 256;
        int r = idx >> 4, c4 = (idx & 15) * 4;
        f32x4 v = *reinterpret_cast<const f32x4*>(
            &W[(size_t)(k0 + r) * DK + n0 + c4]);
        tile[c4 + 0][r] = (bf16)v[0];
        tile[c4 + 1][r] = (bf16)v[1];
        tile[c4 + 2][r] = (bf16)v[2];
        tile[c4 + 3][r] = (bf16)v[3];
    }
    __syncthreads();
    bf16* out = Wt + (size_t)blockIdx.z * DK * D_MODEL;
    #pragma unroll
    for (int i = 0; i < 2; ++i) {
        int idx = t + i * 256;
        int rr = idx >> 3, cc = (idx & 7) * 8;
        *reinterpret_cast<bf16x8*>(&out[(size_t)(n0 + rr) * D_MODEL + k0 + cc]) =
            *reinterpret_cast<const bf16x8*>(&tile[rr][cc]);
    }
}

// ---------------------------------------------------------------------------
// Kernel 1: QKV projection GEMM (R5/R9-proven, byte-identical). X f32 x Wt
// bf16, M-tile 64, BK 64, 4 waves; reg-staged double-buffer, f32->bf16 on
// LDS store. [.][72] pads: word-stride ≡ 4 (mod 32) -> b128 at bank floor.
// ---------------------------------------------------------------------------
__global__ __launch_bounds__(256) void proj_kernel(
    const float* __restrict__ X, const bf16* __restrict__ Wt,
    bf16* __restrict__ Qs, bf16* __restrict__ Kb, bf16* __restrict__ Vt)
{
    __shared__ bf16 Xs[64][72];
    __shared__ bf16 Ws[128][72];
    int mt = blockIdx.x, mat = blockIdx.y;
    const bf16* W = Wt + (size_t)mat * DK * D_MODEL;
    int t = threadIdx.x;
    int wave = t >> 6, lane = t & 63;
    int lq = lane & 15, g = lane >> 4;
    int row0 = mt * 64;

    f32x4 acc[4][2];
    #pragma unroll
    for (int m = 0; m < 4; ++m)
        #pragma unroll
        for (int n = 0; n < 2; ++n) acc[m][n] = f32x4{0.f, 0.f, 0.f, 0.f};

    f32x4  rxf[4];
    bf16x8 rw[4];
    auto LOADR = [&](int k0) {
        #pragma unroll
        for (int i = 0; i < 4; ++i) {
            int u = t + i * 256, r = u >> 4, c4 = u & 15;
            rxf[i] = *reinterpret_cast<const f32x4*>(
                &X[(size_t)(row0 + r) * D_MODEL + k0 + c4 * 4]);
        }
        #pragma unroll
        for (int i = 0; i < 4; ++i) {
            int u = t + i * 256, r = u >> 3, c8 = u & 7;
            rw[i] = *reinterpret_cast<const bf16x8*>(
                &W[(size_t)r * D_MODEL + k0 + c8 * 8]);
        }
    };
    auto STORER = [&]() {
        #pragma unroll
        for (int i = 0; i < 4; ++i) {
            int u = t + i * 256, r = u >> 4, c4 = u & 15;
            bf16x4 h;
            h[0]=(bf16)rxf[i][0]; h[1]=(bf16)rxf[i][1];
            h[2]=(bf16)rxf[i][2]; h[3]=(bf16)rxf[i][3];
            *reinterpret_cast<bf16x4*>(&Xs[r][c4 * 4]) = h;
        }
        #pragma unroll
        for (int i = 0; i < 4; ++i) {
            int u = t + i * 256, r = u >> 3, c8 = u & 7;
            *reinterpret_cast<bf16x8*>(&Ws[r][c8 * 8]) = rw[i];
        }
    };

    LOADR(0);
    for (int ks = 0; ks < 16; ++ks) {
        __syncthreads();
        STORER();
        if (ks + 1 < 16) LOADR((ks + 1) * 64);
        __syncthreads();
        #pragma unroll
        for (int kk = 0; kk < 2; ++kk) {
            bf16x8 a[4];
            #pragma unroll
            for (int mr = 0; mr < 4; ++mr)
                a[mr] = *reinterpret_cast<const bf16x8*>(&Xs[mr * 16 + lq][kk * 32 + g * 8]);
            #pragma unroll
            for (int n = 0; n < 2; ++n) {
                bf16x8 bfr = *reinterpret_cast<const bf16x8*>(
                    &Ws[wave * 32 + n * 16 + lq][kk * 32 + g * 8]);
                #pragma unroll
                for (int mr = 0; mr < 4; ++mr)
                    acc[mr][n] = __builtin_amdgcn_mfma_f32_16x16x32_bf16(a[mr], bfr, acc[mr][n], 0, 0, 0);
            }
        }
    }
    #pragma unroll
    for (int mr = 0; mr < 4; ++mr) {
        int orow = row0 + mr * 16 + g * 4;
        #pragma unroll
        for (int n = 0; n < 2; ++n) {
            int col = wave * 32 + n * 16 + lq;
            if (mat == 0) {
                #pragma unroll
                for (int r = 0; r < 4; ++r)
                    Qs[(size_t)(orow + r) * DK + col] = (bf16)(acc[mr][n][r] * SCALE2);
            } else if (mat == 1) {
                #pragma unroll
                for (int r = 0; r < 4; ++r)
                    Kb[(size_t)(orow + r) * DK + col] = (bf16)acc[mr][n][r];
            } else {
                int bb  = orow >> 11;
                int kv0 = orow & 2047;
                bf16x4 h;
                h[0]=(bf16)acc[mr][n][0]; h[1]=(bf16)acc[mr][n][1];
                h[2]=(bf16)acc[mr][n][2]; h[3]=(bf16)acc[mr][n][3];
                *reinterpret_cast<bf16x4*>(
                    &Vt[((size_t)bb * DK + col) * LSEQ + kv0]) = h;
            }
        }
    }
}

// ---------------------------------------------------------------------------
// Kernel 2: causal flash attention (R16-proven, byte-identical: setprio
// RESTORED — R17 A/B showed removal costs ~0.9us). Variable KV-split
// (<=4 tiles/block, 576 blocks), XCD-pinned batch, reg-prefetch one tile
// ahead, R14 epilogue (S==1 direct store, bf16 partials).
// ---------------------------------------------------------------------------
__global__ __launch_bounds__(256, 3) void attn_kernel(
    const bf16* __restrict__ Qs, const bf16* __restrict__ Kb,
    const bf16* __restrict__ Vt, bf16* __restrict__ Zp,
    float* __restrict__ Mp, float* __restrict__ Lp,
    float* __restrict__ Out, int split)
{
    __shared__ bf16 Ks[64][136];
    __shared__ bf16 Vs[128][72];
    __shared__ bf16 P[4][16][72];
    int bid = blockIdx.x;
    int b, qblk, s;
    if (split) {
        int xcd = bid & 7, u = bid >> 3;      // u in [0,72)
        b = xcd >> 1;                         // XCD-pinned batch (KV L2-fit)
        int n2 = (u << 1) | (xcd & 1);        // interleave: balance XCD halves
        int q = 0, off = 0;
        while (off + ((q >> 2) + 1) <= n2) { off += (q >> 2) + 1; ++q; }
        qblk = q;
        s = n2 - off;
    } else {
        b = bid >> 5;
        qblk = bid & 31;
        s = 0;
    }
    int t = threadIdx.x;
    int wave = t >> 6, lane = t & 63;
    int lq = lane & 15, g = lane >> 4;
    int qw16 = qblk * 4 + wave;
    int qg = qw16 * 16 + lq;

    int nt = qblk + 1;                   // 64-kv tiles, same for all 4 waves
    int t0 = split ? 4 * s : 0;
    int t1 = split ? min(4 * s + 4, nt) : nt;

    const bf16* Kbase = Kb + (size_t)b * LSEQ * DK;
    const bf16* Vbase = Vt + (size_t)b * DK * LSEQ;

    const bf16* Qrow = Qs + ((size_t)b * LSEQ + qg) * DK;
    bf16x8 qf[4];
    #pragma unroll
    for (int ks = 0; ks < 4; ++ks)
        qf[ks] = *reinterpret_cast<const bf16x8*>(&Qrow[ks * 32 + g * 8]);

    f32x4 z[8];
    #pragma unroll
    for (int i = 0; i < 8; ++i) z[i] = f32x4{0.f, 0.f, 0.f, 0.f};
    float mrun = -3.0e38f, lrun = 0.f;

    bf16x8 kreg[4], vreg[4];
    auto LOADKV = [&](int kvb) {
        #pragma unroll
        for (int i = 0; i < 4; ++i) {        // K: 64 rows x 16 chunks
            int u = t + i * 256, r = u >> 4, c = u & 15;
            kreg[i] = *reinterpret_cast<const bf16x8*>(
                &Kbase[(size_t)(kvb + r) * DK + c * 8]);
        }
        #pragma unroll
        for (int i = 0; i < 4; ++i) {        // V: 128 rows x 8 chunks
            int u = t + i * 256, d = u >> 3, c = u & 7;
            vreg[i] = *reinterpret_cast<const bf16x8*>(
                &Vbase[(size_t)d * LSEQ + kvb + c * 8]);
        }
    };
    auto STOREKV = [&]() {
        #pragma unroll
        for (int i = 0; i < 4; ++i) {
            int u = t + i * 256, r = u >> 4, c = u & 15;
            *reinterpret_cast<bf16x8*>(&Ks[r][c * 8]) = kreg[i];
        }
        #pragma unroll
        for (int i = 0; i < 4; ++i) {
            int u = t + i * 256, d = u >> 3, c = u & 7;
            *reinterpret_cast<bf16x8*>(&Vs[d][c * 8]) = vreg[i];
        }
    };

    LOADKV(t0 * 64);
    for (int ti = t0; ti < t1; ++ti) {
        int kvb = ti * 64;
        __syncthreads();             // prev tile's readers done
        STOREKV();
        if (ti + 1 < t1) LOADKV((ti + 1) * 64);   // hide under compute
        __syncthreads();             // LDS tile visible

        f32x4 sc[4];
        #pragma unroll
        for (int jj = 0; jj < 4; ++jj) sc[jj] = f32x4{0.f, 0.f, 0.f, 0.f};
        __builtin_amdgcn_s_setprio(1);
        #pragma unroll
        for (int jj = 0; jj < 4; ++jj)
            #pragma unroll
            for (int ks = 0; ks < 4; ++ks) {
                bf16x8 a = *reinterpret_cast<const bf16x8*>(
                    &Ks[jj * 16 + lq][ks * 32 + g * 8]);
                sc[jj] = __builtin_amdgcn_mfma_f32_16x16x32_bf16(a, qf[ks], sc[jj], 0, 0, 0);
            }
        __builtin_amdgcn_s_setprio(0);

        float sv[16];
        if (ti == nt - 1) {          // only the diagonal tile masks
            #pragma unroll
            for (int jj = 0; jj < 4; ++jj)
                #pragma unroll
                for (int r = 0; r < 4; ++r) {
                    int kv0 = kvb + jj * 16 + g * 4 + r;
                    sv[jj * 4 + r] = (kv0 <= qg) ? sc[jj][r] : -3.0e38f;
                }
        } else {
            #pragma unroll
            for (int jj = 0; jj < 4; ++jj)
                #pragma unroll
                for (int r = 0; r < 4; ++r) sv[jj * 4 + r] = sc[jj][r];
        }
        float mt = sv[0];
        #pragma unroll
        for (int i = 1; i < 16; ++i) mt = fmaxf(mt, sv[i]);
        mt = fmaxf(mt, __shfl_xor(mt, 16));
        mt = fmaxf(mt, __shfl_xor(mt, 32));
        if (!__all(mt <= mrun)) {
            float mnew  = fmaxf(mrun, mt);
            float alpha = exp2f(mrun - mnew);
            lrun *= alpha;
            #pragma unroll
            for (int i = 0; i < 8; ++i) {
                z[i][0] *= alpha; z[i][1] *= alpha; z[i][2] *= alpha; z[i][3] *= alpha;
            }
            mrun = mnew;
        }
        float psum = 0.f;
        #pragma unroll
        for (int jj = 0; jj < 4; ++jj) {
            bf16x4 pb;
            #pragma unroll
            for (int r = 0; r < 4; ++r) {
                float e = exp2f(sv[jj * 4 + r] - mrun);
                psum += e;
                pb[r] = (bf16)e;
            }
            *reinterpret_cast<bf16x4*>(&P[wave][lq][jj * 16 + g * 4]) = pb;
        }
        psum += __shfl_xor(psum, 16);
        psum += __shfl_xor(psum, 32);
        lrun += psum;
        __builtin_amdgcn_s_setprio(1);
        #pragma unroll
        for (int sl = 0; sl < 2; ++sl) {
            bf16x8 pf = *reinterpret_cast<const bf16x8*>(&P[wave][lq][sl * 32 + g * 8]);
            #pragma unroll
            for (int dt = 0; dt < 8; ++dt) {
                bf16x8 av = *reinterpret_cast<const bf16x8*>(
                    &Vs[dt * 16 + lq][sl * 32 + g * 8]);
                z[dt] = __builtin_amdgcn_mfma_f32_16x16x32_bf16(av, pf, z[dt], 0, 0, 0);
            }
        }
        __builtin_amdgcn_s_setprio(0);
    }

    int S = (qblk >> 2) + 1;
    if (!split || S == 1) {
        // this block owns the whole kv range for its rows: write Out directly
        float inv = 1.f / lrun;
        float* orow = Out + ((size_t)b * LSEQ + qg) * DK;
        #pragma unroll
        for (int dt = 0; dt < 8; ++dt) {
            f32x4 v;
            v[0]=z[dt][0]*inv; v[1]=z[dt][1]*inv; v[2]=z[dt][2]*inv; v[3]=z[dt][3]*inv;
            *reinterpret_cast<f32x4*>(&orow[dt * 16 + g * 4]) = v;
        }
    } else {
        size_t T = ((size_t)(b * NQT + qw16) * 8 + s);   // stride 8 slices
        bf16* zp = Zp + T * (16 * 128);
        #pragma unroll
        for (int dt = 0; dt < 8; ++dt) {
            bf16x4 h;
            h[0]=(bf16)z[dt][0]; h[1]=(bf16)z[dt][1];
            h[2]=(bf16)z[dt][2]; h[3]=(bf16)z[dt][3];
            *reinterpret_cast<bf16x4*>(&zp[lq * 128 + dt * 16 + g * 4]) = h;
        }
        if (g == 0) {
            Mp[T * 16 + lq] = mrun;
            Lp[T * 16 + lq] = lrun;
        }
    }
}

// ---------------------------------------------------------------------------
// Kernel 3: merge split-KV partials (bf16 Zp). qblk 0-3 (qt<16) were stored
// directly by attn -> grid covers qt 16..127 only. S(qt) = (qt>>4)+1 >= 2.
// ---------------------------------------------------------------------------
__global__ __launch_bounds__(256) void combine_kernel(
    const bf16* __restrict__ Zp, const float* __restrict__ Mp,
    const float* __restrict__ Lp, float* __restrict__ Out)
{
    int qt = blockIdx.x + 16, b = blockIdx.y;
    int S  = (qt >> 4) + 1;
    int t  = threadIdx.x;
    int r  = t >> 4;
    int d0 = (t & 15) * 8;
    size_t Tbase = (size_t)(b * NQT + qt) * 8;

    float m = -3.0e38f;
    for (int s = 0; s < S; ++s)
        m = fmaxf(m, Mp[(Tbase + s) * 16 + r]);

    float L = 0.f;
    float a[8] = {0.f, 0.f, 0.f, 0.f, 0.f, 0.f, 0.f, 0.f};
    for (int s = 0; s < S; ++s) {
        float w = exp2f(Mp[(Tbase + s) * 16 + r] - m);
        L += w * Lp[(Tbase + s) * 16 + r];
        bf16x8 v = *reinterpret_cast<const bf16x8*>(
            &Zp[(Tbase + s) * (16 * 128) + r * 128 + d0]);
        #pragma unroll
        for (int j = 0; j < 8; ++j) a[j] += w * (float)v[j];
    }
    float inv = 1.f / L;
    float* orow = Out + ((size_t)b * LSEQ + qt * 16 + r) * DK + d0;
    f32x4 o0, o1;
    o0[0]=a[0]*inv; o0[1]=a[1]*inv; o0[2]=a[2]*inv; o0[3]=a[3]*inv;
    o1[0]=a[4]*inv; o1[1]=a[5]*inv; o1[2]=a[6]*inv; o1[3]=a[7]*inv;
    *reinterpret_cast<f32x4*>(&orow[0]) = o0;
    *reinterpret_cast<f32x4*>(&orow[4]) = o1;
}

// ---------------------------------------------------------------------------
extern "C" void kernel_launch(void* const* d_in, const int* in_sizes, int n_in,
                              void* d_out, int out_size, void* d_ws, size_t ws_size,
                              hipStream_t stream)
{
    const float* X  = (const float*)d_in[0];
    const float* Wq = (const float*)d_in[1];
    const float* Wk = (const float*)d_in[2];
    const float* Wv = (const float*)d_in[3];
    float* Out = (float*)d_out;

    char* ws = (char*)d_ws;
    // layout: Wt @0 (768KB) ; Qs @1MB ; Kb @3MB ; Vt @5MB ; Zp @7MB (16MB bf16) ;
    //         Mp / Lp after (256KB each). Total ~23.5MB.
    bf16* Wt = (bf16*)(ws);
    bf16* Qs = (bf16*)(ws + ((size_t)1 << 20));
    bf16* Kb = (bf16*)(ws + ((size_t)3 << 20));
    bf16* Vt = (bf16*)(ws + ((size_t)5 << 20));
    size_t base = (size_t)7 << 20;

    size_t zp_bytes = (size_t)NB * NQT * 8 * 16 * 128 * 2;   // 16 MB (bf16)
    size_t ml_bytes = (size_t)NB * NQT * 8 * 16 * 4;         // 256 KB each
    int split = (ws_size >= base + zp_bytes + 2 * ml_bytes) ? 1 : 0;

    bf16*  Zp = (bf16*)(ws + base);
    float* Mp = (float*)(ws + base + zp_bytes);
    float* Lp = (float*)(ws + base + zp_bytes + ml_bytes);

    hipLaunchKernelGGL(wt_kernel,   dim3(16, 2, 3), dim3(256), 0, stream, Wq, Wk, Wv, Wt);
    hipLaunchKernelGGL(proj_kernel, dim3(128, 3),   dim3(256), 0, stream, X, Wt, Qs, Kb, Vt);
    hipLaunchKernelGGL(attn_kernel, dim3(split ? 576 : NB * 32), dim3(256), 0, stream,
                       Qs, Kb, Vt, Zp, Mp, Lp, Out, split);
    if (split)
        hipLaunchKernelGGL(combine_kernel, dim3(112, NB), dim3(256), 0, stream,
                           Zp, Mp, Lp, Out);
}